// Round 1
// baseline (342.065 us; speedup 1.0000x reference)
//
#include <hip/hip_runtime.h>

// FlattenHead: compact valid rows of x[B,T,D] (fp32) into out, where row (b,t)
// is valid iff t < seq_lens[b]. Output row order = row-major (b,t) order, so
// out[prefix[b]+t, :] = x[b, t, :]. Pure memory-bound row gather.

#define DD 1024   // feature dim (floats per row)
#define TT 4096   // rows per batch

// Build exclusive prefix sum of seq_lens into prefix[0..n].
// Dtype defense: harness may hand us int32 or raw int64; pick whichever
// interpretation's total matches total_rows (= out_size / D).
__global__ void prefix_kernel(const void* __restrict__ seq_raw, int n,
                              int total_rows, int* __restrict__ prefix) {
    if (blockIdx.x == 0 && threadIdx.x == 0) {
        const int*       s32 = (const int*)seq_raw;
        const long long* s64 = (const long long*)seq_raw;
        long long sum32 = 0;
        for (int i = 0; i < n; ++i) sum32 += (long long)s32[i];
        const bool use32 = (sum32 == (long long)total_rows);
        int acc = 0;
        for (int i = 0; i < n; ++i) {
            prefix[i] = acc;
            acc += use32 ? s32[i] : (int)s64[i];
        }
        prefix[n] = acc;
    }
}

// One block per output row; 256 threads x float4 = 4096 B = one row.
__global__ __launch_bounds__(256) void gather_rows(
        const float* __restrict__ x, const int* __restrict__ prefix,
        float* __restrict__ out, int n_b) {
    const int r = blockIdx.x;
    // b = largest index with prefix[b] <= r  (uniform 16-iter scalar scan)
    int b = 0;
    for (int i = 1; i <= n_b; ++i) b += (prefix[i] <= r) ? 1 : 0;
    const int t = r - prefix[b];
    const float4* __restrict__ src =
        (const float4*)(x + ((size_t)b * TT + (size_t)t) * DD);
    float4* __restrict__ dst = (float4*)(out + (size_t)r * DD);
    dst[threadIdx.x] = src[threadIdx.x];
}

extern "C" void kernel_launch(void* const* d_in, const int* in_sizes, int n_in,
                              void* d_out, int out_size, void* d_ws, size_t ws_size,
                              hipStream_t stream) {
    const float* x   = (const float*)d_in[0];
    const void*  seq = d_in[1];
    const int    n_b = in_sizes[1];          // B = 16
    float*       out = (float*)d_out;
    int*      prefix = (int*)d_ws;           // n_b+1 ints of scratch

    const int total_rows = out_size / DD;

    prefix_kernel<<<1, 64, 0, stream>>>(seq, n_b, total_rows, prefix);
    if (total_rows > 0) {
        gather_rows<<<total_rows, 256, 0, stream>>>(x, prefix, out, n_b);
    }
}